// Round 11
// baseline (1310.201 us; speedup 1.0000x reference)
//
#include <hip/hip_runtime.h>
#include <hip/hip_bf16.h>

typedef unsigned short u16;
typedef short short8 __attribute__((ext_vector_type(8)));
typedef float f32x4 __attribute__((ext_vector_type(4)));

// B=16, N=4096, S=1024, K=32, D=64; MLP 67->64->64->128
#define NBLK_PASS 4096   // 524288 rows / 128

// ---- workspace layout (bytes) ----
#define WS_XYZT   0u
#define WS_PTSH   786432u
#define WS_PTSL   (WS_PTSH + 8388608u)
#define WS_NEWXYZ (WS_PTSL + 8388608u)
#define WS_BALL   (WS_NEWXYZ + 196608u)
#define WS_W0F    (WS_BALL + 2097152u)
#define WS_W1F    (WS_W0F + 24576u)
#define WS_W2F    (WS_W1F + 16384u)
#define WS_P0     (WS_W2F + 32768u)
#define WS_P1     (WS_P0 + 2097152u)
#define WS_P2     (WS_P1 + 2097152u)
#define WS_PR     (WS_P2 + 4194304u)
#define WS_AC0    (WS_PR + 65536u)
#define WS_AC1    (WS_AC0 + 1024u)
#define WS_AC2    (WS_AC1 + 1024u)

__device__ __forceinline__ void split2(float v, u16& h, u16& l) {
  __hip_bfloat16 bh = __float2bfloat16(v);
  float r = v - __bfloat162float(bh);
  __hip_bfloat16 bl = __float2bfloat16(r);
  h = *reinterpret_cast<u16*>(&bh);
  l = *reinterpret_cast<u16*>(&bl);
}

// wave64 u64 max via DPP (VALU-speed) — verified bit-exact in R6/R7.
#define DPP_MAX64(K, CTRL) { \
  unsigned int lo_ = (unsigned int)(K), hi_ = (unsigned int)((K) >> 32); \
  unsigned int mlo_ = (unsigned int)__builtin_amdgcn_update_dpp(0, (int)lo_, CTRL, 0xF, 0xF, true); \
  unsigned int mhi_ = (unsigned int)__builtin_amdgcn_update_dpp(0, (int)hi_, CTRL, 0xF, 0xF, true); \
  unsigned long long m_ = ((unsigned long long)mhi_ << 32) | mlo_; \
  if (m_ > (K)) (K) = m_; }

#define DPP_CHAIN(K) \
  DPP_MAX64(K, 0x111) DPP_MAX64(K, 0x112) DPP_MAX64(K, 0x114) DPP_MAX64(K, 0x118) \
  DPP_MAX64(K, 0x142) DPP_MAX64(K, 0x143)

// ============ front: dual-group FPS (2 batches/block, per-group spin barrier) + prep + transposes
// blocks 0..7: FPS {2b, 2b+1}; 8: weight prep; 9..136: xyz-T; 137..1160: pts-T/split
__global__ __launch_bounds__(512, 1) void front_k(
    const float* __restrict__ xyz, const float* __restrict__ pts,
    const float* __restrict__ w0, const float* __restrict__ w1, const float* __restrict__ w2,
    float* __restrict__ xyzT, u16* __restrict__ ptsH, u16* __restrict__ ptsL,
    float* __restrict__ newxyz, float* __restrict__ out0,
    u16* __restrict__ w0f, u16* __restrict__ w1f, u16* __restrict__ w2f)
{
  __shared__ __align__(16) char sm[106656];
  int bid = blockIdx.x, tid = threadIdx.x;

  if (bid < 8) {
    // ---- dual-group FPS: group g = tid>>8 owns batch bid*2+g; arithmetic per chain is the
    //      verified R7 form (byte-identical). Each group syncs via its OWN LDS spin barrier so
    //      the two chains can drift out of phase and hide each other's latency tail.
    int g = tid >> 8, gtid = tid & 255;
    int lane = tid & 63, wid4 = (tid >> 6) & 3;
    int batch = bid*2 + g;
    float* lx = (float*)sm + (size_t)g*12288;   // 3*4096 floats per group
    float* ly = lx + 4096;
    float* lz = ly + 4096;
    int* sIdx = (int*)(sm + 98304) + g*1024;
    unsigned long long* red = (unsigned long long*)(sm + 106496) + g*8;   // [2][4]
    unsigned* sctr = (unsigned*)(sm + 106624);   // [2]
    unsigned* sgen = sctr + 2;                   // [2]

    if (tid < 2) { sctr[tid] = 0u; sgen[tid] = 0u; }

    const float4* sx = (const float4*)(xyz + (size_t)(batch*3 + 0)*4096);
    const float4* sy = (const float4*)(xyz + (size_t)(batch*3 + 1)*4096);
    const float4* sz = (const float4*)(xyz + (size_t)(batch*3 + 2)*4096);
    for (int i = gtid; i < 1024; i += 256) {
      ((float4*)lx)[i] = sx[i]; ((float4*)ly)[i] = sy[i]; ((float4*)lz)[i] = sz[i];
    }
    __syncthreads();

    float px[16], py[16], pz[16], dist[16];
    #pragma unroll
    for (int i = 0; i < 16; ++i) {
      int p = gtid + 256*i;
      px[i] = lx[p]; py[i] = ly[p]; pz[i] = lz[p]; dist[i] = 1e10f;
    }
    unsigned int lo0 = 4095u - (unsigned int)gtid;
    int far = 0;
    for (int t = 0; t < 1024; ++t) {
      if (gtid == 0) sIdx[t] = far;
      if (t == 1023) break;
      float cx = lx[far], cy = ly[far], cz = lz[far];
      float bestnd = -1.f; unsigned int bestlow = 0u;
      #pragma unroll
      for (int i = 0; i < 16; ++i) {
        // exact numpy order: ((dx*dx + dy*dy) + dz*dz), no FMA
        float dx = __fsub_rn(px[i], cx);
        float dy = __fsub_rn(py[i], cy);
        float dz = __fsub_rn(pz[i], cz);
        float d = __fadd_rn(__fadd_rn(__fmul_rn(dx,dx), __fmul_rn(dy,dy)), __fmul_rn(dz,dz));
        float nd = fminf(dist[i], d);
        dist[i] = nd;
        if (nd > bestnd) { bestnd = nd; bestlow = lo0 - 256u*i; }  // strict >: first max = min idx
      }
      unsigned long long k = ((unsigned long long)__float_as_uint(bestnd) << 32) | bestlow;
      DPP_CHAIN(k)
      if (lane == 63) red[(t & 1)*4 + wid4] = k;   // lane 63 holds wave max
      // ---- per-group sense-reversing barrier (4 waves) ----
      {
        __threadfence_block();                      // drain this wave's red[] write
        unsigned gen = ((volatile unsigned*)sgen)[g];
        asm volatile("" ::: "memory");
        if (lane == 0) {
          unsigned old = atomicAdd(&sctr[g], 1u);
          if (old == 3u) {                          // last wave of the group
            sctr[g] = 0u;
            __threadfence_block();
            ((volatile unsigned*)sgen)[g] = gen + 1u;
          }
        }
        while (((volatile unsigned*)sgen)[g] == gen) __builtin_amdgcn_s_sleep(1);
      }
      const unsigned long long* rr = red + (t & 1)*4;
      unsigned long long m = rr[0];
      #pragma unroll
      for (int w = 1; w < 4; ++w) { unsigned long long o = rr[w]; if (o > m) m = o; }
      far = 4095 - (int)(unsigned int)(m & 0xffffffffull);
    }
    __syncthreads();
    for (int t = gtid; t < 1024; t += 256) {
      int fi = sIdx[t];
      float x = lx[fi], y = ly[fi], z = lz[fi];
      size_t nb = ((size_t)batch*1024 + t)*3;
      newxyz[nb + 0] = x; newxyz[nb + 1] = y; newxyz[nb + 2] = z;
      out0[(size_t)(batch*3 + 0)*1024 + t] = x;
      out0[(size_t)(batch*3 + 1)*1024 + t] = y;
      out0[(size_t)(batch*3 + 2)*1024 + t] = z;
    }
  } else if (bid == 8) {
    // ---------------- weights -> split bf16 MFMA B-frags (512t, verified R6) ----------------
    for (int e = tid; e < 6144; e += 512) {
      int j = e & 7, l = (e >> 3) & 63, ct = (e >> 9) & 3, ks = e >> 11;
      int kk = ks*32 + (l >> 4)*8 + j, col = ct*16 + (l & 15);
      float v = 0.f;
      if (kk < 67) { int orow = (kk < 64) ? (kk + 3) : (kk - 64); v = w0[orow*64 + col]; }
      u16 h, lo; split2(v, h, lo);
      w0f[e] = h; w0f[6144 + e] = lo;
    }
    for (int e = tid; e < 4096; e += 512) {
      int j = e & 7, l = (e >> 3) & 63, ct = (e >> 9) & 3, ks = e >> 11;
      int kk = ks*32 + (l >> 4)*8 + j, col = ct*16 + (l & 15);
      u16 h, lo; split2(w1[kk*64 + col], h, lo);
      w1f[e] = h; w1f[4096 + e] = lo;
    }
    for (int e = tid; e < 8192; e += 512) {
      int j = e & 7, l = (e >> 3) & 63, ct = (e >> 9) & 3, ks = (e >> 11) & 1, cg = e >> 12;
      int kk = ks*32 + (l >> 4)*8 + j, col = cg*64 + ct*16 + (l & 15);
      u16 h, lo; split2(w2[kk*128 + col], h, lo);
      w2f[e] = h; w2f[8192 + e] = lo;
    }
  } else if (bid < 137) {
    // ---------------- xyz [B,3,N] -> xyzT [B,N,3] f32 (512t, verified R6) ----------------
    int i = (bid - 9)*512 + tid;
    int b = i >> 12, n = i & 4095;
    float x = xyz[(b*3 + 0)*4096 + n];
    float y = xyz[(b*3 + 1)*4096 + n];
    float z = xyz[(b*3 + 2)*4096 + n];
    xyzT[(size_t)i*3 + 0] = x; xyzT[(size_t)i*3 + 1] = y; xyzT[(size_t)i*3 + 2] = z;
  } else {
    // ---------------- pts [B,64,N] -> split bf16 planes [B,N,64] (512t, verified R6) --------
    int bx = bid - 137;
    u16* th = (u16*)sm;             // 64*68
    u16* tl = th + 64*68;
    int b = bx >> 6, nt = bx & 63;
    int j = tid & 63, dq = tid >> 6;   // dq 0..7
    #pragma unroll
    for (int db = 0; db < 8; ++db) {
      int d = db*8 + dq;
      float v = pts[((size_t)(b*64 + d))*4096 + nt*64 + j];
      u16 h, lo; split2(v, h, lo);
      th[j*68 + d] = h; tl[j*68 + d] = lo;
    }
    __syncthreads();
    int row = tid >> 3, q = tid & 7;
    size_t o = ((size_t)(b*4096 + nt*64 + row))*64 + q*8;
    const u16* sh = th + row*68 + q*8;
    const u16* sl = tl + row*68 + q*8;
    uint2 h0 = *(const uint2*)(sh), h1 = *(const uint2*)(sh + 4);
    uint2 l0 = *(const uint2*)(sl), l1 = *(const uint2*)(sl + 4);
    *(uint2*)(ptsH + o) = h0; *(uint2*)(ptsH + o + 4) = h1;
    *(uint2*)(ptsL + o) = l0; *(uint2*)(ptsL + o + 4) = l1;
  }
}

// ================= ball query (verified exact: do not touch) =================
__global__ __launch_bounds__(256) void ball_k(const float* __restrict__ xyz,
                                              const float* __restrict__ newxyz,
                                              int* __restrict__ ballidx) {
  __shared__ __align__(16) float lx[4096], ly[4096], lz[4096], ldn[4096];
  int b = blockIdx.x >> 5, tid = threadIdx.x, lane = tid & 63, wid = tid >> 6;
  const float4* sx = (const float4*)(xyz + (size_t)(b*3 + 0)*4096);
  const float4* sy = (const float4*)(xyz + (size_t)(b*3 + 1)*4096);
  const float4* sz = (const float4*)(xyz + (size_t)(b*3 + 2)*4096);
  for (int i = tid; i < 1024; i += 256) {
    ((float4*)lx)[i] = sx[i]; ((float4*)ly)[i] = sy[i]; ((float4*)lz)[i] = sz[i];
  }
  __syncthreads();
  for (int i = tid; i < 4096; i += 256) {
    float x = lx[i], y = ly[i], z = lz[i];
    ldn[i] = __fadd_rn(__fadd_rn(__fmul_rn(x,x), __fmul_rn(y,y)), __fmul_rn(z,z));
  }
  __syncthreads();
  int s0 = (blockIdx.x & 31)*32 + wid*8;
  for (int ci = 0; ci < 8; ++ci) {
    int s = s0 + ci;
    const float* cp = newxyz + ((size_t)b*1024 + s)*3;
    float cx = cp[0], cy = cp[1], cz = cp[2];
    float sn = __fadd_rn(__fadd_rn(__fmul_rn(cx,cx), __fmul_rn(cy,cy)), __fmul_rn(cz,cz));
    int* orow = ballidx + (((size_t)b << 10) + s)*32;
    int cnt = 0, first = -1;
    for (int ch = 0; ch < 64; ++ch) {
      int p = ch*64 + lane;
      float x = lx[p], y = ly[p], z = lz[p];
      float dot = __fmaf_rn(cz, z, __fmaf_rn(cy, y, __fmul_rn(cx, x)));
      float sqr = __fadd_rn(__fadd_rn(__fmul_rn(-2.0f, dot), sn), ldn[p]);
      bool in = !(sqr > 0.04f);
      unsigned long long mask = __ballot(in);
      if (first < 0 && mask) first = ch*64 + (__ffsll((long long)mask) - 1);
      int rank = cnt + __popcll(mask & ((1ull << lane) - 1ull));
      if (in && rank < 32) orow[rank] = p;
      cnt += __popcll(mask);
      if (cnt >= 32) break;
    }
    if (cnt < 32) {
      int fv = (first < 0) ? 4095 : first;
      if (lane >= cnt && lane < 32) orow[lane] = fv;
    }
  }
}

// ================= split-bf16 MFMA MLP passes (verified) =================
#define LOFF 6144

__device__ __forceinline__ void stats_fin(float* sSt, float* __restrict__ partial,
                                          int C, int tid, int bid) {
  __syncthreads();
  for (int c = tid; c < C; c += 256) {
    float s = sSt[c*2] + sSt[(128 + c)*2] + sSt[(256 + c)*2] + sSt[(384 + c)*2];
    float q = sSt[c*2 + 1] + sSt[(128 + c)*2 + 1] + sSt[(256 + c)*2 + 1] + sSt[(384 + c)*2 + 1];
    partial[(size_t)bid*2*C + c] = s;
    partial[(size_t)bid*2*C + C + c] = q;
  }
}

template<int DEPTH>
__global__ __launch_bounds__(256, 2) void pass_k(
    const int* __restrict__ ballidx,
    const u16* __restrict__ ptsH, const u16* __restrict__ ptsL,
    const float* __restrict__ xyzT, const float* __restrict__ newxyz,
    const u16* __restrict__ w0f, const u16* __restrict__ w1f, const u16* __restrict__ w2f,
    const float* __restrict__ b0, const float* __restrict__ b1, const float* __restrict__ b2,
    const float* __restrict__ ac0, const float* __restrict__ ac1, const float* __restrict__ ac2,
    float* __restrict__ partial, float* __restrict__ outPts)
{
  __shared__ __align__(16) u16 sAh[128*104];
  __shared__ __align__(16) u16 sAl[128*104];
  __shared__ __align__(16) u16 sW[12288];
  int tid = threadIdx.x, lane = tid & 63, wid = tid >> 6;
  int lrow = lane & 15, lkg = lane >> 4;
  int r0 = wid*32;

  {
    int r = tid >> 1, half = tid & 1;
    int R = blockIdx.x*128 + r;
    int b = R >> 15, s = (R & 32767) >> 5;
    int n = ballidx[R];
    size_t o = ((((size_t)b << 12) + n) << 6) + half*32;
    const uint4* srcH = (const uint4*)(ptsH + o);
    const uint4* srcL = (const uint4*)(ptsL + o);
    uint4* dH = (uint4*)(&sAh[r*104 + half*32]);
    uint4* dL = (uint4*)(&sAl[r*104 + half*32]);
    #pragma unroll
    for (int i = 0; i < 4; ++i) { dH[i] = srcH[i]; dL[i] = srcL[i]; }
    if (half) {
      uint4 zz; zz.x = zz.y = zz.z = zz.w = 0u;
      uint4* zH = (uint4*)(&sAh[r*104 + 64]);
      uint4* zL = (uint4*)(&sAl[r*104 + 64]);
      #pragma unroll
      for (int i = 0; i < 4; ++i) { zH[i] = zz; zL[i] = zz; }
      const float* xp = xyzT + (((size_t)b << 12) + n)*3;
      const float* cp = newxyz + (((size_t)b << 10) + s)*3;
      #pragma unroll
      for (int d = 0; d < 3; ++d) {
        u16 h, l; split2(__fsub_rn(xp[d], cp[d]), h, l);
        sAh[r*104 + 64 + d] = h; sAl[r*104 + 64 + d] = l;
      }
    }
  }
  for (int i = tid; i < 768; i += 256) {
    ((uint4*)sW)[i] = ((const uint4*)w0f)[i];
    *(uint4*)(sW + LOFF + i*8) = ((const uint4*)(w0f + 6144))[i];
  }
  __syncthreads();

  f32x4 zv = {0.f, 0.f, 0.f, 0.f};

  f32x4 acc[2][4];
  #pragma unroll
  for (int rt = 0; rt < 2; ++rt)
    #pragma unroll
    for (int ct = 0; ct < 4; ++ct) acc[rt][ct] = zv;
  #pragma unroll
  for (int ks = 0; ks < 3; ++ks) {
    short8 ah[2], al[2];
    #pragma unroll
    for (int rt = 0; rt < 2; ++rt) {
      int ro = (r0 + rt*16 + lrow)*104 + ks*32 + lkg*8;
      ah[rt] = *(const short8*)&sAh[ro];
      al[rt] = *(const short8*)&sAl[ro];
    }
    #pragma unroll
    for (int ct = 0; ct < 4; ++ct) {
      short8 wh = *(const short8*)&sW[((ks*4 + ct)*64 + lane)*8];
      short8 wl = *(const short8*)&sW[LOFF + ((ks*4 + ct)*64 + lane)*8];
      #pragma unroll
      for (int rt = 0; rt < 2; ++rt) {
        acc[rt][ct] = __builtin_amdgcn_mfma_f32_16x16x32_bf16(ah[rt], wh, acc[rt][ct], 0, 0, 0);
        acc[rt][ct] = __builtin_amdgcn_mfma_f32_16x16x32_bf16(al[rt], wh, acc[rt][ct], 0, 0, 0);
        acc[rt][ct] = __builtin_amdgcn_mfma_f32_16x16x32_bf16(ah[rt], wl, acc[rt][ct], 0, 0, 0);
      }
    }
  }

  if constexpr (DEPTH == 1) {
    __syncthreads();
    float* sSt = (float*)sW;
    #pragma unroll
    for (int ct = 0; ct < 4; ++ct) {
      int col = ct*16 + lrow;
      float bv = b0[col], s = 0.f, q = 0.f;
      #pragma unroll
      for (int rt = 0; rt < 2; ++rt)
        #pragma unroll
        for (int r = 0; r < 4; ++r) { float v = acc[rt][ct][r] + bv; s += v; q += v*v; }
      s += __shfl_xor(s, 16, 64); q += __shfl_xor(q, 16, 64);
      s += __shfl_xor(s, 32, 64); q += __shfl_xor(q, 32, 64);
      if (lane < 16) { sSt[(wid*128 + col)*2] = s; sSt[(wid*128 + col)*2 + 1] = q; }
    }
    stats_fin(sSt, partial, 64, tid, blockIdx.x);
    return;
  } else {
    __syncthreads();
    #pragma unroll
    for (int ct = 0; ct < 4; ++ct) {
      int col = ct*16 + lrow;
      float a = ac0[col], cc = fmaf(a, b0[col], ac0[64 + col]);
      #pragma unroll
      for (int rt = 0; rt < 2; ++rt)
        #pragma unroll
        for (int r = 0; r < 4; ++r) {
          float v = fmaxf(fmaf(a, acc[rt][ct][r], cc), 0.f);
          int row = r0 + rt*16 + lkg*4 + r;
          u16 h, l; split2(v, h, l);
          sAh[row*72 + col] = h; sAl[row*72 + col] = l;
        }
    }
    for (int i = tid; i < 512; i += 256) {
      ((uint4*)sW)[i] = ((const uint4*)w1f)[i];
      *(uint4*)(sW + LOFF + i*8) = ((const uint4*)(w1f + 4096))[i];
    }
    __syncthreads();

    #pragma unroll
    for (int rt = 0; rt < 2; ++rt)
      #pragma unroll
      for (int ct = 0; ct < 4; ++ct) acc[rt][ct] = zv;
    #pragma unroll
    for (int ks = 0; ks < 2; ++ks) {
      short8 ah[2], al[2];
      #pragma unroll
      for (int rt = 0; rt < 2; ++rt) {
        int ro = (r0 + rt*16 + lrow)*72 + ks*32 + lkg*8;
        ah[rt] = *(const short8*)&sAh[ro];
        al[rt] = *(const short8*)&sAl[ro];
      }
      #pragma unroll
      for (int ct = 0; ct < 4; ++ct) {
        short8 wh = *(const short8*)&sW[((ks*4 + ct)*64 + lane)*8];
        short8 wl = *(const short8*)&sW[LOFF + ((ks*4 + ct)*64 + lane)*8];
        #pragma unroll
        for (int rt = 0; rt < 2; ++rt) {
          acc[rt][ct] = __builtin_amdgcn_mfma_f32_16x16x32_bf16(ah[rt], wh, acc[rt][ct], 0, 0, 0);
          acc[rt][ct] = __builtin_amdgcn_mfma_f32_16x16x32_bf16(al[rt], wh, acc[rt][ct], 0, 0, 0);
          acc[rt][ct] = __builtin_amdgcn_mfma_f32_16x16x32_bf16(ah[rt], wl, acc[rt][ct], 0, 0, 0);
        }
      }
    }

    if constexpr (DEPTH == 2) {
      __syncthreads();
      float* sSt = (float*)sW;
      #pragma unroll
      for (int ct = 0; ct < 4; ++ct) {
        int col = ct*16 + lrow;
        float bv = b1[col], s = 0.f, q = 0.f;
        #pragma unroll
        for (int rt = 0; rt < 2; ++rt)
          #pragma unroll
          for (int r = 0; r < 4; ++r) { float v = acc[rt][ct][r] + bv; s += v; q += v*v; }
        s += __shfl_xor(s, 16, 64); q += __shfl_xor(q, 16, 64);
        s += __shfl_xor(s, 32, 64); q += __shfl_xor(q, 32, 64);
        if (lane < 16) { sSt[(wid*128 + col)*2] = s; sSt[(wid*128 + col)*2 + 1] = q; }
      }
      stats_fin(sSt, partial, 64, tid, blockIdx.x);
      return;
    } else {
      __syncthreads();
      #pragma unroll
      for (int ct = 0; ct < 4; ++ct) {
        int col = ct*16 + lrow;
        float a = ac1[col], cc = fmaf(a, b1[col], ac1[64 + col]);
        #pragma unroll
        for (int rt = 0; rt < 2; ++rt)
          #pragma unroll
          for (int r = 0; r < 4; ++r) {
            float v = fmaxf(fmaf(a, acc[rt][ct][r], cc), 0.f);
            int row = r0 + rt*16 + lkg*4 + r;
            u16 h, l; split2(v, h, l);
            sAh[row*72 + col] = h; sAl[row*72 + col] = l;
          }
      }
      for (int i = tid; i < 512; i += 256) {
        ((uint4*)sW)[i] = ((const uint4*)w2f)[i];
        *(uint4*)(sW + LOFF + i*8) = ((const uint4*)(w2f + 8192))[i];
      }
      __syncthreads();

      float sc[2][4], sq[2][4];
      #pragma unroll
      for (int cg = 0; cg < 2; ++cg) {
        if (cg) {
          __syncthreads();
          for (int i = tid; i < 512; i += 256) {
            ((uint4*)sW)[i] = ((const uint4*)(w2f + 4096))[i];
            *(uint4*)(sW + LOFF + i*8) = ((const uint4*)(w2f + 12288))[i];
          }
          __syncthreads();
        }
        f32x4 acc2[2][4];
        #pragma unroll
        for (int rt = 0; rt < 2; ++rt)
          #pragma unroll
          for (int ct = 0; ct < 4; ++ct) acc2[rt][ct] = zv;
        #pragma unroll
        for (int ks = 0; ks < 2; ++ks) {
          short8 ah[2], al[2];
          #pragma unroll
          for (int rt = 0; rt < 2; ++rt) {
            int ro = (r0 + rt*16 + lrow)*72 + ks*32 + lkg*8;
            ah[rt] = *(const short8*)&sAh[ro];
            al[rt] = *(const short8*)&sAl[ro];
          }
          #pragma unroll
          for (int ct = 0; ct < 4; ++ct) {
            short8 wh = *(const short8*)&sW[((ks*4 + ct)*64 + lane)*8];
            short8 wl = *(const short8*)&sW[LOFF + ((ks*4 + ct)*64 + lane)*8];
            #pragma unroll
            for (int rt = 0; rt < 2; ++rt) {
              acc2[rt][ct] = __builtin_amdgcn_mfma_f32_16x16x32_bf16(ah[rt], wh, acc2[rt][ct], 0, 0, 0);
              acc2[rt][ct] = __builtin_amdgcn_mfma_f32_16x16x32_bf16(al[rt], wh, acc2[rt][ct], 0, 0, 0);
              acc2[rt][ct] = __builtin_amdgcn_mfma_f32_16x16x32_bf16(ah[rt], wl, acc2[rt][ct], 0, 0, 0);
            }
          }
        }
        if constexpr (DEPTH == 3) {
          #pragma unroll
          for (int ct = 0; ct < 4; ++ct) {
            int col = cg*64 + ct*16 + lrow;
            float bv = b2[col], s = 0.f, q = 0.f;
            #pragma unroll
            for (int rt = 0; rt < 2; ++rt)
              #pragma unroll
              for (int r = 0; r < 4; ++r) { float v = acc2[rt][ct][r] + bv; s += v; q += v*v; }
            s += __shfl_xor(s, 16, 64); q += __shfl_xor(q, 16, 64);
            s += __shfl_xor(s, 32, 64); q += __shfl_xor(q, 32, 64);
            sc[cg][ct] = s; sq[cg][ct] = q;
          }
        } else {
          int G = blockIdx.x*4 + wid;
          int bb = G >> 10, ss = G & 1023;
          #pragma unroll
          for (int ct = 0; ct < 4; ++ct) {
            int col = cg*64 + ct*16 + lrow;
            float a = ac2[col], cc = fmaf(a, b2[col], ac2[128 + col]);
            float m = 0.f;
            #pragma unroll
            for (int rt = 0; rt < 2; ++rt)
              #pragma unroll
              for (int r = 0; r < 4; ++r)
                m = fmaxf(m, fmaxf(fmaf(a, acc2[rt][ct][r], cc), 0.f));
            m = fmaxf(m, __shfl_xor(m, 16, 64));
            m = fmaxf(m, __shfl_xor(m, 32, 64));
            if (lane < 16) outPts[((size_t)bb*128 + col)*1024 + ss] = m;
          }
        }
      }
      if constexpr (DEPTH == 3) {
        __syncthreads();
        float* sSt = (float*)sW;
        if (lane < 16) {
          #pragma unroll
          for (int cg = 0; cg < 2; ++cg)
            #pragma unroll
            for (int ct = 0; ct < 4; ++ct) {
              int col = cg*64 + ct*16 + lrow;
              sSt[(wid*128 + col)*2] = sc[cg][ct];
              sSt[(wid*128 + col)*2 + 1] = sq[cg][ct];
            }
        }
        stats_fin(sSt, partial, 128, tid, blockIdx.x);
      }
    }
  }
}

// ================= 2-stage deterministic stats reduce =================
__global__ void r1_k(const float* __restrict__ partial, int C, float* __restrict__ pr) {
  int j = blockIdx.x, c = threadIdx.x;
  if (c < 2*C) {
    float s = 0.f;
    for (int i = 0; i < 64; ++i) s += partial[((size_t)(j*64 + i))*2*C + c];
    pr[j*2*C + c] = s;
  }
}
__global__ void r2_k(const float* __restrict__ pr, int C,
                     const float* __restrict__ g, const float* __restrict__ be,
                     float* __restrict__ ac) {
  int c = threadIdx.x;
  if (c < C) {
    float s = 0.f, q = 0.f;
    for (int j = 0; j < 64; ++j) { s += pr[j*2*C + c]; q += pr[j*2*C + C + c]; }
    const float inv = 1.0f / 524288.0f;
    float mu = s*inv, var = q*inv - mu*mu;
    float a = g[c] / sqrtf(var + 1e-5f);
    ac[c] = a; ac[C + c] = be[c] - mu*a;
  }
}

extern "C" void kernel_launch(void* const* d_in, const int* in_sizes, int n_in,
                              void* d_out, int out_size, void* d_ws, size_t ws_size,
                              hipStream_t stream) {
  const float* xyz = (const float*)d_in[0];
  const float* pts = (const float*)d_in[1];
  const float* w0  = (const float*)d_in[2];
  const float* b0  = (const float*)d_in[3];
  const float* g0  = (const float*)d_in[4];
  const float* be0 = (const float*)d_in[5];
  const float* w1  = (const float*)d_in[6];
  const float* b1  = (const float*)d_in[7];
  const float* g1  = (const float*)d_in[8];
  const float* be1 = (const float*)d_in[9];
  const float* w2  = (const float*)d_in[10];
  const float* b2  = (const float*)d_in[11];
  const float* g2  = (const float*)d_in[12];
  const float* be2 = (const float*)d_in[13];
  float* out = (float*)d_out;
  char* ws = (char*)d_ws;

  float* xyzT   = (float*)(ws + WS_XYZT);
  u16*   ptsH   = (u16*)(ws + WS_PTSH);
  u16*   ptsL   = (u16*)(ws + WS_PTSL);
  float* newxyz = (float*)(ws + WS_NEWXYZ);
  int*   ballix = (int*)(ws + WS_BALL);
  u16*   w0f    = (u16*)(ws + WS_W0F);
  u16*   w1f    = (u16*)(ws + WS_W1F);
  u16*   w2f    = (u16*)(ws + WS_W2F);
  float* p0     = (float*)(ws + WS_P0);
  float* p1     = (float*)(ws + WS_P1);
  float* p2     = (float*)(ws + WS_P2);
  float* pr     = (float*)(ws + WS_PR);
  float* ac0    = (float*)(ws + WS_AC0);
  float* ac1    = (float*)(ws + WS_AC1);
  float* ac2    = (float*)(ws + WS_AC2);
  float* outPts = out + 49152;

  front_k<<<1161, 512, 0, stream>>>(xyz, pts, w0, w1, w2, xyzT, ptsH, ptsL,
                                    newxyz, out, w0f, w1f, w2f);
  ball_k<<<512, 256, 0, stream>>>(xyz, newxyz, ballix);

  pass_k<1><<<NBLK_PASS, 256, 0, stream>>>(ballix, ptsH, ptsL, xyzT, newxyz,
      w0f, w1f, w2f, b0, b1, b2, ac0, ac1, ac2, p0, outPts);
  r1_k<<<64, 256, 0, stream>>>(p0, 64, pr);
  r2_k<<<1, 256, 0, stream>>>(pr, 64, g0, be0, ac0);

  pass_k<2><<<NBLK_PASS, 256, 0, stream>>>(ballix, ptsH, ptsL, xyzT, newxyz,
      w0f, w1f, w2f, b0, b1, b2, ac0, ac1, ac2, p1, outPts);
  r1_k<<<64, 256, 0, stream>>>(p1, 64, pr);
  r2_k<<<1, 256, 0, stream>>>(pr, 64, g1, be1, ac1);

  pass_k<3><<<NBLK_PASS, 256, 0, stream>>>(ballix, ptsH, ptsL, xyzT, newxyz,
      w0f, w1f, w2f, b0, b1, b2, ac0, ac1, ac2, p2, outPts);
  r1_k<<<64, 256, 0, stream>>>(p2, 128, pr);
  r2_k<<<1, 256, 0, stream>>>(pr, 128, g2, be2, ac2);

  pass_k<4><<<NBLK_PASS, 256, 0, stream>>>(ballix, ptsH, ptsL, xyzT, newxyz,
      w0f, w1f, w2f, b0, b1, b2, ac0, ac1, ac2, p2, outPts);
}

// Round 12
// 930.123 us; speedup vs baseline: 1.4086x; 1.4086x over previous
//
#include <hip/hip_runtime.h>
#include <hip/hip_bf16.h>

typedef unsigned short u16;
typedef short short8 __attribute__((ext_vector_type(8)));
typedef float f32x4 __attribute__((ext_vector_type(4)));

// B=16, N=4096, S=1024, K=32, D=64; MLP 67->64->64->128
#define NBLK_PASS 4096   // 524288 rows / 128

// ---- workspace layout (bytes) ----
#define WS_XYZT   0u
#define WS_PTSH   786432u
#define WS_PTSL   (WS_PTSH + 8388608u)
#define WS_NEWXYZ (WS_PTSL + 8388608u)
#define WS_BALL   (WS_NEWXYZ + 196608u)
#define WS_W0F    (WS_BALL + 2097152u)
#define WS_W1F    (WS_W0F + 24576u)
#define WS_W2F    (WS_W1F + 16384u)
#define WS_P0     (WS_W2F + 32768u)
#define WS_P1     (WS_P0 + 2097152u)
#define WS_P2     (WS_P1 + 2097152u)
#define WS_PR     (WS_P2 + 4194304u)
#define WS_AC0    (WS_PR + 65536u)
#define WS_AC1    (WS_AC0 + 1024u)
#define WS_AC2    (WS_AC1 + 1024u)

__device__ __forceinline__ void split2(float v, u16& h, u16& l) {
  __hip_bfloat16 bh = __float2bfloat16(v);
  float r = v - __bfloat162float(bh);
  __hip_bfloat16 bl = __float2bfloat16(r);
  h = *reinterpret_cast<u16*>(&bh);
  l = *reinterpret_cast<u16*>(&bl);
}

// wave64 u64 max via DPP (VALU-speed) — verified bit-exact in R6/R7.
#define DPP_MAX64(K, CTRL) { \
  unsigned int lo_ = (unsigned int)(K), hi_ = (unsigned int)((K) >> 32); \
  unsigned int mlo_ = (unsigned int)__builtin_amdgcn_update_dpp(0, (int)lo_, CTRL, 0xF, 0xF, true); \
  unsigned int mhi_ = (unsigned int)__builtin_amdgcn_update_dpp(0, (int)hi_, CTRL, 0xF, 0xF, true); \
  unsigned long long m_ = ((unsigned long long)mhi_ << 32) | mlo_; \
  if (m_ > (K)) (K) = m_; }

#define DPP_CHAIN(K) \
  DPP_MAX64(K, 0x111) DPP_MAX64(K, 0x112) DPP_MAX64(K, 0x114) DPP_MAX64(K, 0x118) \
  DPP_MAX64(K, 0x142) DPP_MAX64(K, 0x143)

// ================= front: FPS(256t, 4 waves, DPP, serial-scan argmax) + prep + transposes =====
// blocks 0..15: FPS; 16: weight prep; 17..272: xyz transpose; 273..1296: pts transpose/split
__global__ __launch_bounds__(256) void front_k(
    const float* __restrict__ xyz, const float* __restrict__ pts,
    const float* __restrict__ w0, const float* __restrict__ w1, const float* __restrict__ w2,
    float* __restrict__ xyzT, u16* __restrict__ ptsH, u16* __restrict__ ptsL,
    float* __restrict__ newxyz, float* __restrict__ out0,
    u16* __restrict__ w0f, u16* __restrict__ w1f, u16* __restrict__ w2f)
{
  __shared__ __align__(16) char sm[53376];
  int bid = blockIdx.x, tid = threadIdx.x;

  if (bid < 16) {
    // ---------------- FPS: exact argmax (verified arithmetic, R7 form: do not touch) ----------
    float* lx = (float*)sm; float* ly = lx + 4096; float* lz = ly + 4096;
    int* sIdx = (int*)(sm + 49152);
    unsigned long long* red = (unsigned long long*)(sm + 53248);  // [2][4]
    int b = bid, lane = tid & 63, wid = tid >> 6;
    const float4* sx = (const float4*)(xyz + (size_t)(b*3 + 0)*4096);
    const float4* sy = (const float4*)(xyz + (size_t)(b*3 + 1)*4096);
    const float4* sz = (const float4*)(xyz + (size_t)(b*3 + 2)*4096);
    for (int i = tid; i < 1024; i += 256) {
      ((float4*)lx)[i] = sx[i]; ((float4*)ly)[i] = sy[i]; ((float4*)lz)[i] = sz[i];
    }
    __syncthreads();
    float px[16], py[16], pz[16], dist[16];
    #pragma unroll
    for (int i = 0; i < 16; ++i) {
      int p = tid + 256*i;
      px[i] = lx[p]; py[i] = ly[p]; pz[i] = lz[p]; dist[i] = 1e10f;
    }
    unsigned int lo0 = 4095u - (unsigned int)tid;
    int far = 0;
    for (int t = 0; t < 1024; ++t) {
      if (tid == 0) sIdx[t] = far;
      if (t == 1023) break;
      float cx = lx[far], cy = ly[far], cz = lz[far];
      float bestnd = -1.f; unsigned int bestlow = 0u;
      #pragma unroll
      for (int i = 0; i < 16; ++i) {
        // exact numpy order: ((dx*dx + dy*dy) + dz*dz), no FMA
        float dx = __fsub_rn(px[i], cx);
        float dy = __fsub_rn(py[i], cy);
        float dz = __fsub_rn(pz[i], cz);
        float d = __fadd_rn(__fadd_rn(__fmul_rn(dx,dx), __fmul_rn(dy,dy)), __fmul_rn(dz,dz));
        float nd = fminf(dist[i], d);
        dist[i] = nd;
        if (nd > bestnd) { bestnd = nd; bestlow = lo0 - 256u*i; }  // strict >: first max = min idx
      }
      unsigned long long k = ((unsigned long long)__float_as_uint(bestnd) << 32) | bestlow;
      DPP_CHAIN(k)
      if (lane == 63) red[(t & 1)*4 + wid] = k;   // lane 63 holds wave max
      __syncthreads();
      const unsigned long long* rr = red + (t & 1)*4;
      unsigned long long m = rr[0];
      #pragma unroll
      for (int w = 1; w < 4; ++w) { unsigned long long o = rr[w]; if (o > m) m = o; }
      far = 4095 - (int)(unsigned int)(m & 0xffffffffull);
    }
    __syncthreads();
    for (int t = tid; t < 1024; t += 256) {
      int fi = sIdx[t];
      float x = lx[fi], y = ly[fi], z = lz[fi];
      size_t nb = ((size_t)b*1024 + t)*3;
      newxyz[nb + 0] = x; newxyz[nb + 1] = y; newxyz[nb + 2] = z;
      out0[(size_t)(b*3 + 0)*1024 + t] = x;
      out0[(size_t)(b*3 + 1)*1024 + t] = y;
      out0[(size_t)(b*3 + 2)*1024 + t] = z;
    }
  } else if (bid == 16) {
    // ---------------- weights -> split bf16 MFMA B-frags ----------------
    for (int e = tid; e < 6144; e += 256) {
      int j = e & 7, l = (e >> 3) & 63, ct = (e >> 9) & 3, ks = e >> 11;
      int kk = ks*32 + (l >> 4)*8 + j, col = ct*16 + (l & 15);
      float v = 0.f;
      if (kk < 67) { int orow = (kk < 64) ? (kk + 3) : (kk - 64); v = w0[orow*64 + col]; }
      u16 h, lo; split2(v, h, lo);
      w0f[e] = h; w0f[6144 + e] = lo;
    }
    for (int e = tid; e < 4096; e += 256) {
      int j = e & 7, l = (e >> 3) & 63, ct = (e >> 9) & 3, ks = e >> 11;
      int kk = ks*32 + (l >> 4)*8 + j, col = ct*16 + (l & 15);
      u16 h, lo; split2(w1[kk*64 + col], h, lo);
      w1f[e] = h; w1f[4096 + e] = lo;
    }
    for (int e = tid; e < 8192; e += 256) {
      int j = e & 7, l = (e >> 3) & 63, ct = (e >> 9) & 3, ks = (e >> 11) & 1, cg = e >> 12;
      int kk = ks*32 + (l >> 4)*8 + j, col = cg*64 + ct*16 + (l & 15);
      u16 h, lo; split2(w2[kk*128 + col], h, lo);
      w2f[e] = h; w2f[8192 + e] = lo;
    }
  } else if (bid < 273) {
    // ---------------- xyz [B,3,N] -> xyzT [B,N,3] f32 ----------------
    int i = (bid - 17)*256 + tid;
    int b = i >> 12, n = i & 4095;
    float x = xyz[(b*3 + 0)*4096 + n];
    float y = xyz[(b*3 + 1)*4096 + n];
    float z = xyz[(b*3 + 2)*4096 + n];
    xyzT[(size_t)i*3 + 0] = x; xyzT[(size_t)i*3 + 1] = y; xyzT[(size_t)i*3 + 2] = z;
  } else {
    // ---------------- pts [B,64,N] -> split bf16 planes [B,N,64] ----------------
    int bx = bid - 273;
    u16* th = (u16*)sm;             // 64*68
    u16* tl = th + 64*68;
    int b = bx >> 6, nt = bx & 63;
    int j = tid & 63, dq = tid >> 6;   // dq 0..3
    #pragma unroll
    for (int db = 0; db < 16; ++db) {
      int d = db*4 + dq;
      float v = pts[((size_t)(b*64 + d))*4096 + nt*64 + j];
      u16 h, lo; split2(v, h, lo);
      th[j*68 + d] = h; tl[j*68 + d] = lo;
    }
    __syncthreads();
    int row = tid >> 2, q = tid & 3;
    size_t o = ((size_t)(b*4096 + nt*64 + row))*64 + q*16;
    const u16* sh = th + row*68 + q*16;
    const u16* sl = tl + row*68 + q*16;
    #pragma unroll
    for (int i = 0; i < 4; ++i) {
      *(uint2*)(ptsH + o + i*4) = *(const uint2*)(sh + i*4);
      *(uint2*)(ptsL + o + i*4) = *(const uint2*)(sl + i*4);
    }
  }
}

// ================= ball query (verified exact: do not touch) =================
__global__ __launch_bounds__(256) void ball_k(const float* __restrict__ xyz,
                                              const float* __restrict__ newxyz,
                                              int* __restrict__ ballidx) {
  __shared__ __align__(16) float lx[4096], ly[4096], lz[4096], ldn[4096];
  int b = blockIdx.x >> 5, tid = threadIdx.x, lane = tid & 63, wid = tid >> 6;
  const float4* sx = (const float4*)(xyz + (size_t)(b*3 + 0)*4096);
  const float4* sy = (const float4*)(xyz + (size_t)(b*3 + 1)*4096);
  const float4* sz = (const float4*)(xyz + (size_t)(b*3 + 2)*4096);
  for (int i = tid; i < 1024; i += 256) {
    ((float4*)lx)[i] = sx[i]; ((float4*)ly)[i] = sy[i]; ((float4*)lz)[i] = sz[i];
  }
  __syncthreads();
  for (int i = tid; i < 4096; i += 256) {
    float x = lx[i], y = ly[i], z = lz[i];
    ldn[i] = __fadd_rn(__fadd_rn(__fmul_rn(x,x), __fmul_rn(y,y)), __fmul_rn(z,z));
  }
  __syncthreads();
  int s0 = (blockIdx.x & 31)*32 + wid*8;
  for (int ci = 0; ci < 8; ++ci) {
    int s = s0 + ci;
    const float* cp = newxyz + ((size_t)b*1024 + s)*3;
    float cx = cp[0], cy = cp[1], cz = cp[2];
    float sn = __fadd_rn(__fadd_rn(__fmul_rn(cx,cx), __fmul_rn(cy,cy)), __fmul_rn(cz,cz));
    int* orow = ballidx + (((size_t)b << 10) + s)*32;
    int cnt = 0, first = -1;
    for (int ch = 0; ch < 64; ++ch) {
      int p = ch*64 + lane;
      float x = lx[p], y = ly[p], z = lz[p];
      float dot = __fmaf_rn(cz, z, __fmaf_rn(cy, y, __fmul_rn(cx, x)));
      float sqr = __fadd_rn(__fadd_rn(__fmul_rn(-2.0f, dot), sn), ldn[p]);
      bool in = !(sqr > 0.04f);
      unsigned long long mask = __ballot(in);
      if (first < 0 && mask) first = ch*64 + (__ffsll((long long)mask) - 1);
      int rank = cnt + __popcll(mask & ((1ull << lane) - 1ull));
      if (in && rank < 32) orow[rank] = p;
      cnt += __popcll(mask);
      if (cnt >= 32) break;
    }
    if (cnt < 32) {
      int fv = (first < 0) ? 4095 : first;
      if (lane >= cnt && lane < 32) orow[lane] = fv;
    }
  }
}

// ================= split-bf16 MFMA MLP passes (verified) =================
#define LOFF 6144

__device__ __forceinline__ void stats_fin(float* sSt, float* __restrict__ partial,
                                          int C, int tid, int bid) {
  __syncthreads();
  for (int c = tid; c < C; c += 256) {
    float s = sSt[c*2] + sSt[(128 + c)*2] + sSt[(256 + c)*2] + sSt[(384 + c)*2];
    float q = sSt[c*2 + 1] + sSt[(128 + c)*2 + 1] + sSt[(256 + c)*2 + 1] + sSt[(384 + c)*2 + 1];
    partial[(size_t)bid*2*C + c] = s;
    partial[(size_t)bid*2*C + C + c] = q;
  }
}

template<int DEPTH>
__global__ __launch_bounds__(256, 2) void pass_k(
    const int* __restrict__ ballidx,
    const u16* __restrict__ ptsH, const u16* __restrict__ ptsL,
    const float* __restrict__ xyzT, const float* __restrict__ newxyz,
    const u16* __restrict__ w0f, const u16* __restrict__ w1f, const u16* __restrict__ w2f,
    const float* __restrict__ b0, const float* __restrict__ b1, const float* __restrict__ b2,
    const float* __restrict__ ac0, const float* __restrict__ ac1, const float* __restrict__ ac2,
    float* __restrict__ partial, float* __restrict__ outPts)
{
  __shared__ __align__(16) u16 sAh[128*104];
  __shared__ __align__(16) u16 sAl[128*104];
  __shared__ __align__(16) u16 sW[12288];
  int tid = threadIdx.x, lane = tid & 63, wid = tid >> 6;
  int lrow = lane & 15, lkg = lane >> 4;
  int r0 = wid*32;

  {
    int r = tid >> 1, half = tid & 1;
    int R = blockIdx.x*128 + r;
    int b = R >> 15, s = (R & 32767) >> 5;
    int n = ballidx[R];
    size_t o = ((((size_t)b << 12) + n) << 6) + half*32;
    const uint4* srcH = (const uint4*)(ptsH + o);
    const uint4* srcL = (const uint4*)(ptsL + o);
    uint4* dH = (uint4*)(&sAh[r*104 + half*32]);
    uint4* dL = (uint4*)(&sAl[r*104 + half*32]);
    #pragma unroll
    for (int i = 0; i < 4; ++i) { dH[i] = srcH[i]; dL[i] = srcL[i]; }
    if (half) {
      uint4 zz; zz.x = zz.y = zz.z = zz.w = 0u;
      uint4* zH = (uint4*)(&sAh[r*104 + 64]);
      uint4* zL = (uint4*)(&sAl[r*104 + 64]);
      #pragma unroll
      for (int i = 0; i < 4; ++i) { zH[i] = zz; zL[i] = zz; }
      const float* xp = xyzT + (((size_t)b << 12) + n)*3;
      const float* cp = newxyz + (((size_t)b << 10) + s)*3;
      #pragma unroll
      for (int d = 0; d < 3; ++d) {
        u16 h, l; split2(__fsub_rn(xp[d], cp[d]), h, l);
        sAh[r*104 + 64 + d] = h; sAl[r*104 + 64 + d] = l;
      }
    }
  }
  for (int i = tid; i < 768; i += 256) {
    ((uint4*)sW)[i] = ((const uint4*)w0f)[i];
    *(uint4*)(sW + LOFF + i*8) = ((const uint4*)(w0f + 6144))[i];
  }
  __syncthreads();

  f32x4 zv = {0.f, 0.f, 0.f, 0.f};

  f32x4 acc[2][4];
  #pragma unroll
  for (int rt = 0; rt < 2; ++rt)
    #pragma unroll
    for (int ct = 0; ct < 4; ++ct) acc[rt][ct] = zv;
  #pragma unroll
  for (int ks = 0; ks < 3; ++ks) {
    short8 ah[2], al[2];
    #pragma unroll
    for (int rt = 0; rt < 2; ++rt) {
      int ro = (r0 + rt*16 + lrow)*104 + ks*32 + lkg*8;
      ah[rt] = *(const short8*)&sAh[ro];
      al[rt] = *(const short8*)&sAl[ro];
    }
    #pragma unroll
    for (int ct = 0; ct < 4; ++ct) {
      short8 wh = *(const short8*)&sW[((ks*4 + ct)*64 + lane)*8];
      short8 wl = *(const short8*)&sW[LOFF + ((ks*4 + ct)*64 + lane)*8];
      #pragma unroll
      for (int rt = 0; rt < 2; ++rt) {
        acc[rt][ct] = __builtin_amdgcn_mfma_f32_16x16x32_bf16(ah[rt], wh, acc[rt][ct], 0, 0, 0);
        acc[rt][ct] = __builtin_amdgcn_mfma_f32_16x16x32_bf16(al[rt], wh, acc[rt][ct], 0, 0, 0);
        acc[rt][ct] = __builtin_amdgcn_mfma_f32_16x16x32_bf16(ah[rt], wl, acc[rt][ct], 0, 0, 0);
      }
    }
  }

  if constexpr (DEPTH == 1) {
    __syncthreads();
    float* sSt = (float*)sW;
    #pragma unroll
    for (int ct = 0; ct < 4; ++ct) {
      int col = ct*16 + lrow;
      float bv = b0[col], s = 0.f, q = 0.f;
      #pragma unroll
      for (int rt = 0; rt < 2; ++rt)
        #pragma unroll
        for (int r = 0; r < 4; ++r) { float v = acc[rt][ct][r] + bv; s += v; q += v*v; }
      s += __shfl_xor(s, 16, 64); q += __shfl_xor(q, 16, 64);
      s += __shfl_xor(s, 32, 64); q += __shfl_xor(q, 32, 64);
      if (lane < 16) { sSt[(wid*128 + col)*2] = s; sSt[(wid*128 + col)*2 + 1] = q; }
    }
    stats_fin(sSt, partial, 64, tid, blockIdx.x);
    return;
  } else {
    __syncthreads();
    #pragma unroll
    for (int ct = 0; ct < 4; ++ct) {
      int col = ct*16 + lrow;
      float a = ac0[col], cc = fmaf(a, b0[col], ac0[64 + col]);
      #pragma unroll
      for (int rt = 0; rt < 2; ++rt)
        #pragma unroll
        for (int r = 0; r < 4; ++r) {
          float v = fmaxf(fmaf(a, acc[rt][ct][r], cc), 0.f);
          int row = r0 + rt*16 + lkg*4 + r;
          u16 h, l; split2(v, h, l);
          sAh[row*72 + col] = h; sAl[row*72 + col] = l;
        }
    }
    for (int i = tid; i < 512; i += 256) {
      ((uint4*)sW)[i] = ((const uint4*)w1f)[i];
      *(uint4*)(sW + LOFF + i*8) = ((const uint4*)(w1f + 4096))[i];
    }
    __syncthreads();

    #pragma unroll
    for (int rt = 0; rt < 2; ++rt)
      #pragma unroll
      for (int ct = 0; ct < 4; ++ct) acc[rt][ct] = zv;
    #pragma unroll
    for (int ks = 0; ks < 2; ++ks) {
      short8 ah[2], al[2];
      #pragma unroll
      for (int rt = 0; rt < 2; ++rt) {
        int ro = (r0 + rt*16 + lrow)*72 + ks*32 + lkg*8;
        ah[rt] = *(const short8*)&sAh[ro];
        al[rt] = *(const short8*)&sAl[ro];
      }
      #pragma unroll
      for (int ct = 0; ct < 4; ++ct) {
        short8 wh = *(const short8*)&sW[((ks*4 + ct)*64 + lane)*8];
        short8 wl = *(const short8*)&sW[LOFF + ((ks*4 + ct)*64 + lane)*8];
        #pragma unroll
        for (int rt = 0; rt < 2; ++rt) {
          acc[rt][ct] = __builtin_amdgcn_mfma_f32_16x16x32_bf16(ah[rt], wh, acc[rt][ct], 0, 0, 0);
          acc[rt][ct] = __builtin_amdgcn_mfma_f32_16x16x32_bf16(al[rt], wh, acc[rt][ct], 0, 0, 0);
          acc[rt][ct] = __builtin_amdgcn_mfma_f32_16x16x32_bf16(ah[rt], wl, acc[rt][ct], 0, 0, 0);
        }
      }
    }

    if constexpr (DEPTH == 2) {
      __syncthreads();
      float* sSt = (float*)sW;
      #pragma unroll
      for (int ct = 0; ct < 4; ++ct) {
        int col = ct*16 + lrow;
        float bv = b1[col], s = 0.f, q = 0.f;
        #pragma unroll
        for (int rt = 0; rt < 2; ++rt)
          #pragma unroll
          for (int r = 0; r < 4; ++r) { float v = acc[rt][ct][r] + bv; s += v; q += v*v; }
        s += __shfl_xor(s, 16, 64); q += __shfl_xor(q, 16, 64);
        s += __shfl_xor(s, 32, 64); q += __shfl_xor(q, 32, 64);
        if (lane < 16) { sSt[(wid*128 + col)*2] = s; sSt[(wid*128 + col)*2 + 1] = q; }
      }
      stats_fin(sSt, partial, 64, tid, blockIdx.x);
      return;
    } else {
      __syncthreads();
      #pragma unroll
      for (int ct = 0; ct < 4; ++ct) {
        int col = ct*16 + lrow;
        float a = ac1[col], cc = fmaf(a, b1[col], ac1[64 + col]);
        #pragma unroll
        for (int rt = 0; rt < 2; ++rt)
          #pragma unroll
          for (int r = 0; r < 4; ++r) {
            float v = fmaxf(fmaf(a, acc[rt][ct][r], cc), 0.f);
            int row = r0 + rt*16 + lkg*4 + r;
            u16 h, l; split2(v, h, l);
            sAh[row*72 + col] = h; sAl[row*72 + col] = l;
          }
      }
      for (int i = tid; i < 512; i += 256) {
        ((uint4*)sW)[i] = ((const uint4*)w2f)[i];
        *(uint4*)(sW + LOFF + i*8) = ((const uint4*)(w2f + 8192))[i];
      }
      __syncthreads();

      float sc[2][4], sq[2][4];
      #pragma unroll
      for (int cg = 0; cg < 2; ++cg) {
        if (cg) {
          __syncthreads();
          for (int i = tid; i < 512; i += 256) {
            ((uint4*)sW)[i] = ((const uint4*)(w2f + 4096))[i];
            *(uint4*)(sW + LOFF + i*8) = ((const uint4*)(w2f + 12288))[i];
          }
          __syncthreads();
        }
        f32x4 acc2[2][4];
        #pragma unroll
        for (int rt = 0; rt < 2; ++rt)
          #pragma unroll
          for (int ct = 0; ct < 4; ++ct) acc2[rt][ct] = zv;
        #pragma unroll
        for (int ks = 0; ks < 2; ++ks) {
          short8 ah[2], al[2];
          #pragma unroll
          for (int rt = 0; rt < 2; ++rt) {
            int ro = (r0 + rt*16 + lrow)*72 + ks*32 + lkg*8;
            ah[rt] = *(const short8*)&sAh[ro];
            al[rt] = *(const short8*)&sAl[ro];
          }
          #pragma unroll
          for (int ct = 0; ct < 4; ++ct) {
            short8 wh = *(const short8*)&sW[((ks*4 + ct)*64 + lane)*8];
            short8 wl = *(const short8*)&sW[LOFF + ((ks*4 + ct)*64 + lane)*8];
            #pragma unroll
            for (int rt = 0; rt < 2; ++rt) {
              acc2[rt][ct] = __builtin_amdgcn_mfma_f32_16x16x32_bf16(ah[rt], wh, acc2[rt][ct], 0, 0, 0);
              acc2[rt][ct] = __builtin_amdgcn_mfma_f32_16x16x32_bf16(al[rt], wh, acc2[rt][ct], 0, 0, 0);
              acc2[rt][ct] = __builtin_amdgcn_mfma_f32_16x16x32_bf16(ah[rt], wl, acc2[rt][ct], 0, 0, 0);
            }
          }
        }
        if constexpr (DEPTH == 3) {
          #pragma unroll
          for (int ct = 0; ct < 4; ++ct) {
            int col = cg*64 + ct*16 + lrow;
            float bv = b2[col], s = 0.f, q = 0.f;
            #pragma unroll
            for (int rt = 0; rt < 2; ++rt)
              #pragma unroll
              for (int r = 0; r < 4; ++r) { float v = acc2[rt][ct][r] + bv; s += v; q += v*v; }
            s += __shfl_xor(s, 16, 64); q += __shfl_xor(q, 16, 64);
            s += __shfl_xor(s, 32, 64); q += __shfl_xor(q, 32, 64);
            sc[cg][ct] = s; sq[cg][ct] = q;
          }
        } else {
          int G = blockIdx.x*4 + wid;
          int bb = G >> 10, ss = G & 1023;
          #pragma unroll
          for (int ct = 0; ct < 4; ++ct) {
            int col = cg*64 + ct*16 + lrow;
            float a = ac2[col], cc = fmaf(a, b2[col], ac2[128 + col]);
            float m = 0.f;
            #pragma unroll
            for (int rt = 0; rt < 2; ++rt)
              #pragma unroll
              for (int r = 0; r < 4; ++r)
                m = fmaxf(m, fmaxf(fmaf(a, acc2[rt][ct][r], cc), 0.f));
            m = fmaxf(m, __shfl_xor(m, 16, 64));
            m = fmaxf(m, __shfl_xor(m, 32, 64));
            if (lane < 16) outPts[((size_t)bb*128 + col)*1024 + ss] = m;
          }
        }
      }
      if constexpr (DEPTH == 3) {
        __syncthreads();
        float* sSt = (float*)sW;
        if (lane < 16) {
          #pragma unroll
          for (int cg = 0; cg < 2; ++cg)
            #pragma unroll
            for (int ct = 0; ct < 4; ++ct) {
              int col = cg*64 + ct*16 + lrow;
              sSt[(wid*128 + col)*2] = sc[cg][ct];
              sSt[(wid*128 + col)*2 + 1] = sq[cg][ct];
            }
        }
        stats_fin(sSt, partial, 128, tid, blockIdx.x);
      }
    }
  }
}

// ================= 2-stage deterministic stats reduce =================
__global__ void r1_k(const float* __restrict__ partial, int C, float* __restrict__ pr) {
  int j = blockIdx.x, c = threadIdx.x;
  if (c < 2*C) {
    float s = 0.f;
    for (int i = 0; i < 64; ++i) s += partial[((size_t)(j*64 + i))*2*C + c];
    pr[j*2*C + c] = s;
  }
}
__global__ void r2_k(const float* __restrict__ pr, int C,
                     const float* __restrict__ g, const float* __restrict__ be,
                     float* __restrict__ ac) {
  int c = threadIdx.x;
  if (c < C) {
    float s = 0.f, q = 0.f;
    for (int j = 0; j < 64; ++j) { s += pr[j*2*C + c]; q += pr[j*2*C + C + c]; }
    const float inv = 1.0f / 524288.0f;
    float mu = s*inv, var = q*inv - mu*mu;
    float a = g[c] / sqrtf(var + 1e-5f);
    ac[c] = a; ac[C + c] = be[c] - mu*a;
  }
}

extern "C" void kernel_launch(void* const* d_in, const int* in_sizes, int n_in,
                              void* d_out, int out_size, void* d_ws, size_t ws_size,
                              hipStream_t stream) {
  const float* xyz = (const float*)d_in[0];
  const float* pts = (const float*)d_in[1];
  const float* w0  = (const float*)d_in[2];
  const float* b0  = (const float*)d_in[3];
  const float* g0  = (const float*)d_in[4];
  const float* be0 = (const float*)d_in[5];
  const float* w1  = (const float*)d_in[6];
  const float* b1  = (const float*)d_in[7];
  const float* g1  = (const float*)d_in[8];
  const float* be1 = (const float*)d_in[9];
  const float* w2  = (const float*)d_in[10];
  const float* b2  = (const float*)d_in[11];
  const float* g2  = (const float*)d_in[12];
  const float* be2 = (const float*)d_in[13];
  float* out = (float*)d_out;
  char* ws = (char*)d_ws;

  float* xyzT   = (float*)(ws + WS_XYZT);
  u16*   ptsH   = (u16*)(ws + WS_PTSH);
  u16*   ptsL   = (u16*)(ws + WS_PTSL);
  float* newxyz = (float*)(ws + WS_NEWXYZ);
  int*   ballix = (int*)(ws + WS_BALL);
  u16*   w0f    = (u16*)(ws + WS_W0F);
  u16*   w1f    = (u16*)(ws + WS_W1F);
  u16*   w2f    = (u16*)(ws + WS_W2F);
  float* p0     = (float*)(ws + WS_P0);
  float* p1     = (float*)(ws + WS_P1);
  float* p2     = (float*)(ws + WS_P2);
  float* pr     = (float*)(ws + WS_PR);
  float* ac0    = (float*)(ws + WS_AC0);
  float* ac1    = (float*)(ws + WS_AC1);
  float* ac2    = (float*)(ws + WS_AC2);
  float* outPts = out + 49152;

  front_k<<<1297, 256, 0, stream>>>(xyz, pts, w0, w1, w2, xyzT, ptsH, ptsL,
                                    newxyz, out, w0f, w1f, w2f);
  ball_k<<<512, 256, 0, stream>>>(xyz, newxyz, ballix);

  pass_k<1><<<NBLK_PASS, 256, 0, stream>>>(ballix, ptsH, ptsL, xyzT, newxyz,
      w0f, w1f, w2f, b0, b1, b2, ac0, ac1, ac2, p0, outPts);
  r1_k<<<64, 256, 0, stream>>>(p0, 64, pr);
  r2_k<<<1, 256, 0, stream>>>(pr, 64, g0, be0, ac0);

  pass_k<2><<<NBLK_PASS, 256, 0, stream>>>(ballix, ptsH, ptsL, xyzT, newxyz,
      w0f, w1f, w2f, b0, b1, b2, ac0, ac1, ac2, p1, outPts);
  r1_k<<<64, 256, 0, stream>>>(p1, 64, pr);
  r2_k<<<1, 256, 0, stream>>>(pr, 64, g1, be1, ac1);

  pass_k<3><<<NBLK_PASS, 256, 0, stream>>>(ballix, ptsH, ptsL, xyzT, newxyz,
      w0f, w1f, w2f, b0, b1, b2, ac0, ac1, ac2, p2, outPts);
  r1_k<<<64, 256, 0, stream>>>(p2, 128, pr);
  r2_k<<<1, 256, 0, stream>>>(pr, 128, g2, be2, ac2);

  pass_k<4><<<NBLK_PASS, 256, 0, stream>>>(ballix, ptsH, ptsL, xyzT, newxyz,
      w0f, w1f, w2f, b0, b1, b2, ac0, ac1, ac2, p2, outPts);
}